// Round 1
// baseline (851.147 us; speedup 1.0000x reference)
//
#include <hip/hip_runtime.h>
#include <hip/hip_bf16.h>
#include <math.h>

typedef __bf16 bf16;
typedef __bf16 bf16x8 __attribute__((ext_vector_type(8)));
typedef __bf16 bf16x4 __attribute__((ext_vector_type(4)));
typedef float  f32x4  __attribute__((ext_vector_type(4)));

#define B_  2
#define T_  2048
#define DM  2048
#define H_  32
#define DH  64
#define M_  (B_*T_)   // 4096

__device__ __forceinline__ bf16x8 load8(const bf16* p) {
    return *reinterpret_cast<const bf16x8*>(p);
}

// ---------------- convert fp32 -> bf16 (elementwise) ----------------
__global__ void k_convert(const float* __restrict__ in, bf16* __restrict__ out, int n4) {
    int i = blockIdx.x * blockDim.x + threadIdx.x;
    if (i < n4) {
        float4 v = reinterpret_cast<const float4*>(in)[i];
        bf16x4 o;
        o.x = (bf16)v.x; o.y = (bf16)v.y; o.z = (bf16)v.z; o.w = (bf16)v.w;
        reinterpret_cast<bf16x4*>(out)[i] = o;
    }
}

// ---------------- transpose + convert the 4 weight matrices ----------------
__global__ void k_transposeW(const float* __restrict__ Wq, const float* __restrict__ Wk,
                             const float* __restrict__ Wv, const float* __restrict__ Wo,
                             bf16* __restrict__ WqT, bf16* __restrict__ WkT,
                             bf16* __restrict__ WvT, bf16* __restrict__ WoT) {
    const float* in; bf16* out;
    switch (blockIdx.z) {
        case 0: in = Wq; out = WqT; break;
        case 1: in = Wk; out = WkT; break;
        case 2: in = Wv; out = WvT; break;
        default: in = Wo; out = WoT; break;
    }
    __shared__ float tile[32][33];
    int tx = threadIdx.x, ty = threadIdx.y;
    int x0 = blockIdx.x * 32, y0 = blockIdx.y * 32;
    #pragma unroll
    for (int i = 0; i < 4; i++)
        tile[ty + i*8][tx] = in[(size_t)(y0 + ty + i*8) * DM + x0 + tx];
    __syncthreads();
    #pragma unroll
    for (int i = 0; i < 4; i++)
        out[(size_t)(x0 + ty + i*8) * DM + y0 + tx] = (bf16)tile[tx][ty + i*8];
}

// ---------------- bf16 MFMA GEMM: C[M,N] = A[M,K] @ BT[N,K]^T ----------------
// block 256 (4 waves), tile 64(M) x 64(N), K-chunks of 32. K=N=2048.
template<int OUT_BF16>
__global__ __launch_bounds__(256)
void k_gemm(const bf16* __restrict__ A, const bf16* __restrict__ BT, void* __restrict__ Cout) {
    constexpr int K = 2048, N = 2048;
    __shared__ bf16 ldsB[64 * 40];   // row stride 40 bf16 = 80B (16B-aligned, 2-way banks)
    int tid  = threadIdx.x;
    int lane = tid & 63, w = tid >> 6;
    int l16  = lane & 15, quad = lane >> 4;
    int mbase = blockIdx.y * 64 + w * 16;
    int nbase = blockIdx.x * 64;

    f32x4 acc[4];
    #pragma unroll
    for (int s = 0; s < 4; s++) acc[s] = (f32x4){0.f, 0.f, 0.f, 0.f};

    int sn = tid >> 2, sk = tid & 3;
    const bf16* srcB = BT + (size_t)(nbase + sn) * K + sk * 8;
    const bf16* srcA = A + (size_t)(mbase + l16) * K + quad * 8;

    for (int k0 = 0; k0 < K; k0 += 32) {
        *reinterpret_cast<uint4*>(&ldsB[sn * 40 + sk * 8]) =
            *reinterpret_cast<const uint4*>(srcB + k0);
        __syncthreads();
        bf16x8 a = load8(srcA + k0);
        #pragma unroll
        for (int s = 0; s < 4; s++) {
            bf16x8 b = *reinterpret_cast<bf16x8*>(&ldsB[(s * 16 + l16) * 40 + quad * 8]);
            acc[s] = __builtin_amdgcn_mfma_f32_16x16x32_bf16(a, b, acc[s], 0, 0, 0);
        }
        __syncthreads();
    }

    #pragma unroll
    for (int s = 0; s < 4; s++) {
        #pragma unroll
        for (int r = 0; r < 4; r++) {
            int row = mbase + quad * 4 + r;
            int col = nbase + s * 16 + l16;
            if (OUT_BF16)
                reinterpret_cast<bf16*>(Cout)[(size_t)row * N + col] = (bf16)acc[s][r];
            else
                reinterpret_cast<float*>(Cout)[(size_t)row * N + col] = acc[s][r];
        }
    }
}

// ---------------- RoPE in-place on a [B,T,H,DH] bf16 buffer ----------------
__global__ void k_rope(bf16* __restrict__ buf) {
    int id = blockIdx.x * 256 + threadIdx.x;   // B*T*H*32 = 4194304 threads
    int i = id & 31;
    int h = (id >> 5) & 31;
    int t = (id >> 10) & 2047;
    int b = id >> 21;
    size_t base = ((size_t)(b * T_ + t)) * DM + h * 64;
    // inv_freq = 10000^(-i/32) = exp(-i/32 * ln(10000))
    float inv = expf(-(float)i * (9.210340371976184f / 32.0f));
    float ang = (float)t * inv;
    float s, c;
    sincosf(ang, &s, &c);
    float x1 = (float)buf[base + i];
    float x2 = (float)buf[base + i + 32];
    buf[base + i]      = (bf16)(x1 * c - x2 * s);
    buf[base + i + 32] = (bf16)(x2 * c + x1 * s);
}

// ---------------- v = l1*v1 + l2*v_gemm, transposed to [B,H,DH,T] bf16 -------
__global__ void k_combinev(const float* __restrict__ v1, const bf16* __restrict__ vg,
                           const float* __restrict__ l1p, const float* __restrict__ l2p,
                           bf16* __restrict__ vT) {
    __shared__ float tile[64 * 33];
    float l1 = l1p[0], l2 = l2p[0];
    int b = blockIdx.y >> 5, h = blockIdx.y & 31;
    int t0 = blockIdx.x * 32;
    int tid = threadIdx.x;
    int d = tid & 63, tr = tid >> 6;
    #pragma unroll
    for (int i = 0; i < 8; i++) {
        int t = t0 + i * 4 + tr;
        size_t idx = ((size_t)(b * T_ + t)) * DM + h * 64 + d;
        tile[d * 33 + i * 4 + tr] = l1 * v1[idx] + l2 * (float)vg[idx];
    }
    __syncthreads();
    int tl = tid & 31, dr = tid >> 5;
    #pragma unroll
    for (int j = 0; j < 8; j++) {
        int d2 = dr + j * 8;
        vT[((size_t)((b * H_ + h) * 64 + d2)) * T_ + t0 + tl] = (bf16)tile[d2 * 33 + tl];
    }
}

// ---------------- causal flash attention, 1 wave per (b,h, 16-row q tile) ----
__global__ __launch_bounds__(64)
void k_attn(const bf16* __restrict__ q, const bf16* __restrict__ k,
            const bf16* __restrict__ vT, bf16* __restrict__ o) {
    __shared__ bf16 ldsP[16 * 40];  // P tile: 16 q-rows x 32 keys, row stride 40
    int qt = blockIdx.x;            // 0..127
    int bh = blockIdx.y;            // 0..63
    int b = bh >> 5, h = bh & 31;
    int lane = threadIdx.x;
    int l16 = lane & 15, quad = lane >> 4;

    size_t qrow = (size_t)(b * T_ + qt * 16 + l16) * DM + h * 64;
    bf16x8 aq0 = load8(q + qrow + quad * 8);
    bf16x8 aq1 = load8(q + qrow + 32 + quad * 8);

    f32x4 accO[4];
    #pragma unroll
    for (int s = 0; s < 4; s++) accO[s] = (f32x4){0.f, 0.f, 0.f, 0.f};
    float mst[4] = {-1e30f, -1e30f, -1e30f, -1e30f};
    float lst[4] = {0.f, 0.f, 0.f, 0.f};

    int nkt = (qt + 2) >> 1;                       // ceil((qt+1)*16 / 32)
    const size_t kbase = (size_t)b * T_ * DM + (size_t)h * 64;
    const size_t vbase = (size_t)(b * H_ + h) * 64 * T_;

    for (int kt = 0; kt < nkt; kt++) {
        // ---- scores: two 16-key subtiles, contraction over DH=64 ----
        f32x4 sc[2];
        #pragma unroll
        for (int sub = 0; sub < 2; sub++) {
            int n0 = kt * 32 + sub * 16;
            size_t krow = kbase + (size_t)(n0 + l16) * DM;
            bf16x8 bk0 = load8(k + krow + quad * 8);
            bf16x8 bk1 = load8(k + krow + 32 + quad * 8);
            f32x4 z = (f32x4){0.f, 0.f, 0.f, 0.f};
            z = __builtin_amdgcn_mfma_f32_16x16x32_bf16(aq0, bk0, z, 0, 0, 0);
            z = __builtin_amdgcn_mfma_f32_16x16x32_bf16(aq1, bk1, z, 0, 0, 0);
            sc[sub] = z;
        }
        // ---- online softmax per owned row (rows quad*4 + r) ----
        int qm = qt * 16 + quad * 4;
        #pragma unroll
        for (int r = 0; r < 4; r++) {
            float s0 = sc[0][r] * 0.125f;
            float s1 = sc[1][r] * 0.125f;
            if (kt * 32 + l16      > qm + r) s0 = -1e30f;
            if (kt * 32 + 16 + l16 > qm + r) s1 = -1e30f;
            float mx = fmaxf(s0, s1);
            #pragma unroll
            for (int m = 1; m < 16; m <<= 1) mx = fmaxf(mx, __shfl_xor(mx, m));
            float nm = fmaxf(mst[r], mx);
            float alpha = __expf(mst[r] - nm);
            float p0 = __expf(s0 - nm);
            float p1 = __expf(s1 - nm);
            float rsum = p0 + p1;
            #pragma unroll
            for (int m = 1; m < 16; m <<= 1) rsum += __shfl_xor(rsum, m);
            lst[r] = lst[r] * alpha + rsum;
            mst[r] = nm;
            #pragma unroll
            for (int n2 = 0; n2 < 4; n2++) accO[n2][r] *= alpha;
            ldsP[(quad * 4 + r) * 40 + l16]      = (bf16)p0;
            ldsP[(quad * 4 + r) * 40 + 16 + l16] = (bf16)p1;
        }
        __syncthreads();
        // ---- PV: P (A-layout via LDS) @ V (B from vT rows) ----
        bf16x8 pa = *reinterpret_cast<bf16x8*>(&ldsP[l16 * 40 + quad * 8]);
        #pragma unroll
        for (int n2 = 0; n2 < 4; n2++) {
            bf16x8 bv = load8(vT + vbase + (size_t)(n2 * 16 + l16) * T_ + kt * 32 + quad * 8);
            accO[n2] = __builtin_amdgcn_mfma_f32_16x16x32_bf16(pa, bv, accO[n2], 0, 0, 0);
        }
        __syncthreads();
    }

    // ---- epilogue: O /= l, write bf16 [B,T,H*DH] ----
    #pragma unroll
    for (int n2 = 0; n2 < 4; n2++) {
        #pragma unroll
        for (int r = 0; r < 4; r++) {
            float val = accO[n2][r] / lst[r];
            o[(size_t)(b * T_ + qt * 16 + quad * 4 + r) * DM + h * 64 + n2 * 16 + l16] = (bf16)val;
        }
    }
}

extern "C" void kernel_launch(void* const* d_in, const int* in_sizes, int n_in,
                              void* d_out, int out_size, void* d_ws, size_t ws_size,
                              hipStream_t stream) {
    const float* hs   = (const float*)d_in[0];
    const float* v1   = (const float*)d_in[1];
    const float* lam1 = (const float*)d_in[2];
    const float* Wq   = (const float*)d_in[3];
    const float* Wk   = (const float*)d_in[4];
    const float* Wv   = (const float*)d_in[5];
    const float* Wo   = (const float*)d_in[6];
    const float* lam2 = (const float*)d_in[7];

    char* ws = (char*)d_ws;
    bf16* hs_bf = (bf16*)(ws);                          // 16 MiB
    bf16* WqT   = (bf16*)(ws + 16777216);               // 8 MiB each
    bf16* WkT   = (bf16*)(ws + 25165824);
    bf16* WvT   = (bf16*)(ws + 33554432);
    bf16* WoT   = (bf16*)(ws + 41943040);
    bf16* q_bf  = (bf16*)(ws + 50331648);               // 16 MiB
    bf16* k_bf  = (bf16*)(ws + 67108864);
    bf16* v_bf  = (bf16*)(ws + 83886080);
    bf16* vT_bf = (bf16*)(ws + 100663296);
    bf16* o_bf  = (bf16*)(ws + 117440512);              // ends at 128 MiB

    k_convert<<<8192, 256, 0, stream>>>(hs, hs_bf, 2097152);
    k_transposeW<<<dim3(64, 64, 4), dim3(32, 8), 0, stream>>>(Wq, Wk, Wv, Wo, WqT, WkT, WvT, WoT);

    k_gemm<1><<<dim3(32, 64), 256, 0, stream>>>(hs_bf, WqT, (void*)q_bf);
    k_gemm<1><<<dim3(32, 64), 256, 0, stream>>>(hs_bf, WkT, (void*)k_bf);
    k_gemm<1><<<dim3(32, 64), 256, 0, stream>>>(hs_bf, WvT, (void*)v_bf);

    k_rope<<<16384, 256, 0, stream>>>(q_bf);
    k_rope<<<16384, 256, 0, stream>>>(k_bf);

    k_combinev<<<dim3(64, 64), 256, 0, stream>>>(v1, v_bf, lam1, lam2, vT_bf);

    k_attn<<<dim3(128, 64), 64, 0, stream>>>(q_bf, k_bf, vT_bf, o_bf);

    k_gemm<0><<<dim3(32, 64), 256, 0, stream>>>(o_bf, WoT, d_out);
}

// Round 2
// 832.410 us; speedup vs baseline: 1.0225x; 1.0225x over previous
//
#include <hip/hip_runtime.h>
#include <hip/hip_bf16.h>
#include <math.h>

typedef __bf16 bf16;
typedef __bf16 bf16x8 __attribute__((ext_vector_type(8)));
typedef __bf16 bf16x4 __attribute__((ext_vector_type(4)));
typedef float  f32x4  __attribute__((ext_vector_type(4)));

#define B_  2
#define T_  2048
#define DM  2048
#define H_  32
#define DH  64
#define M_  (B_*T_)   // 4096

__device__ __forceinline__ bf16x8 load8(const bf16* p) {
    return *reinterpret_cast<const bf16x8*>(p);
}

// ---------------- convert fp32 -> bf16 (elementwise) ----------------
__global__ void k_convert(const float* __restrict__ in, bf16* __restrict__ out, int n4) {
    int i = blockIdx.x * blockDim.x + threadIdx.x;
    if (i < n4) {
        float4 v = reinterpret_cast<const float4*>(in)[i];
        bf16x4 o;
        o.x = (bf16)v.x; o.y = (bf16)v.y; o.z = (bf16)v.z; o.w = (bf16)v.w;
        reinterpret_cast<bf16x4*>(out)[i] = o;
    }
}

// ---------------- transpose + convert the 4 weight matrices ----------------
__global__ void k_transposeW(const float* __restrict__ Wq, const float* __restrict__ Wk,
                             const float* __restrict__ Wv, const float* __restrict__ Wo,
                             bf16* __restrict__ WqT, bf16* __restrict__ WkT,
                             bf16* __restrict__ WvT, bf16* __restrict__ WoT) {
    const float* in; bf16* out;
    switch (blockIdx.z) {
        case 0: in = Wq; out = WqT; break;
        case 1: in = Wk; out = WkT; break;
        case 2: in = Wv; out = WvT; break;
        default: in = Wo; out = WoT; break;
    }
    __shared__ float tile[32][33];
    int tx = threadIdx.x, ty = threadIdx.y;
    int x0 = blockIdx.x * 32, y0 = blockIdx.y * 32;
    #pragma unroll
    for (int i = 0; i < 4; i++)
        tile[ty + i*8][tx] = in[(size_t)(y0 + ty + i*8) * DM + x0 + tx];
    __syncthreads();
    #pragma unroll
    for (int i = 0; i < 4; i++)
        out[(size_t)(x0 + ty + i*8) * DM + y0 + tx] = (bf16)tile[tx][ty + i*8];
}

// ---------------- bf16 MFMA GEMM: C[M,N] = A[M,K] @ BT[N,K]^T ----------------
// block 256 (4 waves), tile 64(M) x 64(N), K-chunks of 32. K=N=2048.
template<int OUT_BF16>
__global__ __launch_bounds__(256)
void k_gemm(const bf16* __restrict__ A, const bf16* __restrict__ BT, void* __restrict__ Cout) {
    constexpr int K = 2048, N = 2048;
    __shared__ bf16 ldsB[64 * 40];   // row stride 40 bf16 = 80B (16B-aligned, 2-way banks)
    int tid  = threadIdx.x;
    int lane = tid & 63, w = tid >> 6;
    int l16  = lane & 15, quad = lane >> 4;
    int mbase = blockIdx.y * 64 + w * 16;
    int nbase = blockIdx.x * 64;

    f32x4 acc[4];
    #pragma unroll
    for (int s = 0; s < 4; s++) acc[s] = (f32x4){0.f, 0.f, 0.f, 0.f};

    int sn = tid >> 2, sk = tid & 3;
    const bf16* srcB = BT + (size_t)(nbase + sn) * K + sk * 8;
    const bf16* srcA = A + (size_t)(mbase + l16) * K + quad * 8;

    for (int k0 = 0; k0 < K; k0 += 32) {
        *reinterpret_cast<uint4*>(&ldsB[sn * 40 + sk * 8]) =
            *reinterpret_cast<const uint4*>(srcB + k0);
        __syncthreads();
        bf16x8 a = load8(srcA + k0);
        #pragma unroll
        for (int s = 0; s < 4; s++) {
            bf16x8 b = *reinterpret_cast<bf16x8*>(&ldsB[(s * 16 + l16) * 40 + quad * 8]);
            acc[s] = __builtin_amdgcn_mfma_f32_16x16x32_bf16(a, b, acc[s], 0, 0, 0);
        }
        __syncthreads();
    }

    #pragma unroll
    for (int s = 0; s < 4; s++) {
        #pragma unroll
        for (int r = 0; r < 4; r++) {
            int row = mbase + quad * 4 + r;
            int col = nbase + s * 16 + l16;
            if (OUT_BF16)
                reinterpret_cast<bf16*>(Cout)[(size_t)row * N + col] = (bf16)acc[s][r];
            else
                reinterpret_cast<float*>(Cout)[(size_t)row * N + col] = acc[s][r];
        }
    }
}

// ---------------- RoPE in-place on a [B,T,H,DH] bf16 buffer ----------------
__global__ void k_rope(bf16* __restrict__ buf) {
    int id = blockIdx.x * 256 + threadIdx.x;   // B*T*H*32 = 4194304 threads
    int i = id & 31;
    int h = (id >> 5) & 31;
    int t = (id >> 10) & 2047;
    int b = id >> 21;
    size_t base = ((size_t)(b * T_ + t)) * DM + h * 64;
    float inv = expf(-(float)i * (9.210340371976184f / 32.0f));
    float ang = (float)t * inv;
    float s, c;
    sincosf(ang, &s, &c);
    float x1 = (float)buf[base + i];
    float x2 = (float)buf[base + i + 32];
    buf[base + i]      = (bf16)(x1 * c - x2 * s);
    buf[base + i + 32] = (bf16)(x2 * c + x1 * s);
}

// ---------------- v = l1*v1 + l2*v_gemm, transposed to [B,H,DH,T] bf16 -------
__global__ void k_combinev(const float* __restrict__ v1, const bf16* __restrict__ vg,
                           const float* __restrict__ l1p, const float* __restrict__ l2p,
                           bf16* __restrict__ vT) {
    __shared__ float tile[64 * 33];
    float l1 = l1p[0], l2 = l2p[0];
    int b = blockIdx.y >> 5, h = blockIdx.y & 31;
    int t0 = blockIdx.x * 32;
    int tid = threadIdx.x;
    int d = tid & 63, tr = tid >> 6;
    #pragma unroll
    for (int i = 0; i < 8; i++) {
        int t = t0 + i * 4 + tr;
        size_t idx = ((size_t)(b * T_ + t)) * DM + h * 64 + d;
        tile[d * 33 + i * 4 + tr] = l1 * v1[idx] + l2 * (float)vg[idx];
    }
    __syncthreads();
    int tl = tid & 31, dr = tid >> 5;
    #pragma unroll
    for (int j = 0; j < 8; j++) {
        int d2 = dr + j * 8;
        vT[((size_t)((b * H_ + h) * 64 + d2)) * T_ + t0 + tl] = (bf16)tile[d2 * 33 + tl];
    }
}

// ---------------- causal flash attention ----------------
// block = 256 threads (4 waves), 64 q-rows per block (16 per wave).
// K tile (32 keys x 64 dh) and vT tile (64 dh x 32 keys) staged in LDS,
// shared by all 4 waves. grid (T/64=32, B*H=64).
__global__ __launch_bounds__(256)
void k_attn(const bf16* __restrict__ q, const bf16* __restrict__ k,
            const bf16* __restrict__ vT, bf16* __restrict__ o) {
    __shared__ bf16 ldsK[32 * 72];      // key-major, stride 72 (2-way banks on b128 read)
    __shared__ bf16 ldsV[64 * 40];      // dh-major rows of vT, stride 40
    __shared__ bf16 ldsP[4][16 * 40];   // per-wave P tile, stride 40

    int qt = blockIdx.x;                // 0..31 (64 q-rows each)
    int bh = blockIdx.y;                // 0..63
    int b = bh >> 5, h = bh & 31;
    int tid = threadIdx.x;
    int lane = tid & 63, w = tid >> 6;
    int l16 = lane & 15, quad = lane >> 4;

    // staging indices: K tile needs 32 rows x 128B; V tile 64 rows x 64B
    int kkey = tid >> 3, kseg = tid & 7;    // 8 x 16B per K row
    int vd   = tid >> 2, vseg = tid & 3;    // 4 x 16B per V row
    const size_t kbase = (size_t)b * T_ * DM + (size_t)h * DH;
    const size_t vbase = (size_t)(b * H_ + h) * DH * T_;
    const bf16* ksrc = k + kbase + (size_t)kkey * DM + kseg * 8;
    const bf16* vsrc = vT + vbase + (size_t)vd * T_ + vseg * 8;

    // Q fragments: 16 rows per wave, held in registers for the whole kernel
    int qrow0 = qt * 64 + w * 16;
    size_t qrow = (size_t)(b * T_ + qrow0 + l16) * DM + h * DH;
    bf16x8 aq0 = load8(q + qrow + quad * 8);
    bf16x8 aq1 = load8(q + qrow + 32 + quad * 8);

    f32x4 accO[4];
    #pragma unroll
    for (int s = 0; s < 4; s++) accO[s] = (f32x4){0.f, 0.f, 0.f, 0.f};
    float mst[4] = {-1e30f, -1e30f, -1e30f, -1e30f};
    float lst[4] = {0.f, 0.f, 0.f, 0.f};

    int nkt = 2 * qt + 2;               // block-uniform: keys up to (qt+1)*64

    for (int kt = 0; kt < nkt; kt++) {
        // ---- cooperative stage K,V tile ----
        *reinterpret_cast<uint4*>(&ldsK[kkey * 72 + kseg * 8]) =
            *reinterpret_cast<const uint4*>(ksrc + (size_t)kt * 32 * DM);
        *reinterpret_cast<uint4*>(&ldsV[vd * 40 + vseg * 8]) =
            *reinterpret_cast<const uint4*>(vsrc + kt * 32);
        __syncthreads();

        // ---- scores: two 16-key subtiles ----
        f32x4 sc[2];
        #pragma unroll
        for (int sub = 0; sub < 2; sub++) {
            int key = sub * 16 + l16;
            bf16x8 bk0 = *reinterpret_cast<bf16x8*>(&ldsK[key * 72 + quad * 8]);
            bf16x8 bk1 = *reinterpret_cast<bf16x8*>(&ldsK[key * 72 + 32 + quad * 8]);
            f32x4 z = (f32x4){0.f, 0.f, 0.f, 0.f};
            z = __builtin_amdgcn_mfma_f32_16x16x32_bf16(aq0, bk0, z, 0, 0, 0);
            z = __builtin_amdgcn_mfma_f32_16x16x32_bf16(aq1, bk1, z, 0, 0, 0);
            sc[sub] = z;
        }

        // ---- online softmax per owned row ----
        int qm = qrow0 + quad * 4;
        #pragma unroll
        for (int r = 0; r < 4; r++) {
            float s0 = sc[0][r] * 0.125f;
            float s1 = sc[1][r] * 0.125f;
            if (kt * 32 + l16      > qm + r) s0 = -1e30f;
            if (kt * 32 + 16 + l16 > qm + r) s1 = -1e30f;
            float mx = fmaxf(s0, s1);
            #pragma unroll
            for (int m = 1; m < 16; m <<= 1) mx = fmaxf(mx, __shfl_xor(mx, m));
            float nm = fmaxf(mst[r], mx);
            float alpha = __expf(mst[r] - nm);
            float p0 = __expf(s0 - nm);
            float p1 = __expf(s1 - nm);
            float rsum = p0 + p1;
            #pragma unroll
            for (int m = 1; m < 16; m <<= 1) rsum += __shfl_xor(rsum, m);
            lst[r] = lst[r] * alpha + rsum;
            mst[r] = nm;
            #pragma unroll
            for (int n2 = 0; n2 < 4; n2++) accO[n2][r] *= alpha;
            ldsP[w][(quad * 4 + r) * 40 + l16]      = (bf16)p0;
            ldsP[w][(quad * 4 + r) * 40 + 16 + l16] = (bf16)p1;
        }
        __syncthreads();   // P visible (and keeps waves converged)

        // ---- PV: P (A-layout) @ V (B-frag rows from ldsV) ----
        bf16x8 pa = *reinterpret_cast<bf16x8*>(&ldsP[w][l16 * 40 + quad * 8]);
        #pragma unroll
        for (int n2 = 0; n2 < 4; n2++) {
            bf16x8 bv = *reinterpret_cast<bf16x8*>(&ldsV[(n2 * 16 + l16) * 40 + quad * 8]);
            accO[n2] = __builtin_amdgcn_mfma_f32_16x16x32_bf16(pa, bv, accO[n2], 0, 0, 0);
        }
        __syncthreads();   // protect ldsK/ldsV before next stage
    }

    // ---- epilogue: O /= l, write bf16 [B,T,H*DH] ----
    #pragma unroll
    for (int n2 = 0; n2 < 4; n2++) {
        #pragma unroll
        for (int r = 0; r < 4; r++) {
            float val = accO[n2][r] / lst[r];
            o[(size_t)(b * T_ + qrow0 + quad * 4 + r) * DM + h * DH + n2 * 16 + l16] = (bf16)val;
        }
    }
}

extern "C" void kernel_launch(void* const* d_in, const int* in_sizes, int n_in,
                              void* d_out, int out_size, void* d_ws, size_t ws_size,
                              hipStream_t stream) {
    const float* hs   = (const float*)d_in[0];
    const float* v1   = (const float*)d_in[1];
    const float* lam1 = (const float*)d_in[2];
    const float* Wq   = (const float*)d_in[3];
    const float* Wk   = (const float*)d_in[4];
    const float* Wv   = (const float*)d_in[5];
    const float* Wo   = (const float*)d_in[6];
    const float* lam2 = (const float*)d_in[7];

    char* ws = (char*)d_ws;
    bf16* hs_bf = (bf16*)(ws);                          // 16 MiB
    bf16* WqT   = (bf16*)(ws + 16777216);               // 8 MiB each
    bf16* WkT   = (bf16*)(ws + 25165824);
    bf16* WvT   = (bf16*)(ws + 33554432);
    bf16* WoT   = (bf16*)(ws + 41943040);
    bf16* q_bf  = (bf16*)(ws + 50331648);               // 16 MiB
    bf16* k_bf  = (bf16*)(ws + 67108864);
    bf16* v_bf  = (bf16*)(ws + 83886080);
    bf16* vT_bf = (bf16*)(ws + 100663296);
    bf16* o_bf  = (bf16*)(ws + 117440512);              // ends at 128 MiB

    k_convert<<<8192, 256, 0, stream>>>(hs, hs_bf, 2097152);
    k_transposeW<<<dim3(64, 64, 4), dim3(32, 8), 0, stream>>>(Wq, Wk, Wv, Wo, WqT, WkT, WvT, WoT);

    k_gemm<1><<<dim3(32, 64), 256, 0, stream>>>(hs_bf, WqT, (void*)q_bf);
    k_gemm<1><<<dim3(32, 64), 256, 0, stream>>>(hs_bf, WkT, (void*)k_bf);
    k_gemm<1><<<dim3(32, 64), 256, 0, stream>>>(hs_bf, WvT, (void*)v_bf);

    k_rope<<<16384, 256, 0, stream>>>(q_bf);
    k_rope<<<16384, 256, 0, stream>>>(k_bf);

    k_combinev<<<dim3(64, 64), 256, 0, stream>>>(v1, v_bf, lam1, lam2, vT_bf);

    k_attn<<<dim3(32, 64), 256, 0, stream>>>(q_bf, k_bf, vT_bf, o_bf);

    k_gemm<0><<<dim3(32, 64), 256, 0, stream>>>(o_bf, WoT, d_out);
}

// Round 3
// 512.446 us; speedup vs baseline: 1.6610x; 1.6244x over previous
//
#include <hip/hip_runtime.h>
#include <hip/hip_bf16.h>
#include <math.h>

typedef __bf16 bf16;
typedef __bf16 bf16x8 __attribute__((ext_vector_type(8)));
typedef __bf16 bf16x4 __attribute__((ext_vector_type(4)));
typedef float  f32x4  __attribute__((ext_vector_type(4)));
typedef short  sv4    __attribute__((ext_vector_type(4)));

#define B_  2
#define T_  2048
#define DM  2048
#define H_  32
#define DH  64

__device__ __forceinline__ bf16x8 load8(const bf16* p) {
    return *reinterpret_cast<const bf16x8*>(p);
}

// async global->LDS, 16B per lane; lds dest must be wave-uniform base (+lane*16 implicit)
__device__ __forceinline__ void gld16(const bf16* g, bf16* l) {
    __builtin_amdgcn_global_load_lds(
        (const __attribute__((address_space(1))) unsigned int*)g,
        (__attribute__((address_space(3))) unsigned int*)l, 16, 0, 0);
}

// ---------------- convert fp32 -> bf16 ----------------
__global__ void k_convert(const float* __restrict__ in, bf16* __restrict__ out, int n4) {
    int i = blockIdx.x * blockDim.x + threadIdx.x;
    if (i < n4) {
        float4 v = reinterpret_cast<const float4*>(in)[i];
        bf16x4 o;
        o[0] = (bf16)v.x; o[1] = (bf16)v.y; o[2] = (bf16)v.z; o[3] = (bf16)v.w;
        reinterpret_cast<bf16x4*>(out)[i] = o;
    }
}

// ---------------- transpose + convert weights ----------------
__global__ void k_transposeW(const float* __restrict__ Wq, const float* __restrict__ Wk,
                             const float* __restrict__ Wv, const float* __restrict__ Wo,
                             bf16* __restrict__ WqT, bf16* __restrict__ WkT,
                             bf16* __restrict__ WvT, bf16* __restrict__ WoT) {
    const float* in; bf16* out;
    switch (blockIdx.z) {
        case 0: in = Wq; out = WqT; break;
        case 1: in = Wk; out = WkT; break;
        case 2: in = Wv; out = WvT; break;
        default: in = Wo; out = WoT; break;
    }
    __shared__ float tile[32][33];
    int tx = threadIdx.x, ty = threadIdx.y;
    int x0 = blockIdx.x * 32, y0 = blockIdx.y * 32;
    #pragma unroll
    for (int i = 0; i < 4; i++)
        tile[ty + i*8][tx] = in[(size_t)(y0 + ty + i*8) * DM + x0 + tx];
    __syncthreads();
    #pragma unroll
    for (int i = 0; i < 4; i++)
        out[(size_t)(x0 + ty + i*8) * DM + y0 + tx] = (bf16)tile[tx][ty + i*8];
}

// ---------------- m97-style GEMM: C[M,ldc-range] = A[M,2048] @ BT[N,2048]^T ----
// block 256 = 4 waves (2x2), tile 128x128, K-step 32, global_load_lds staging.
template<int OUT_BF16>
__global__ __launch_bounds__(256)
void k_gemm(const bf16* __restrict__ A, const bf16* __restrict__ BT,
            void* __restrict__ Cout, int ldc) {
    constexpr int K = 2048;
    __shared__ bf16 ldsA[128 * 32];   // row-major, unpadded (global_load_lds layout)
    __shared__ bf16 ldsB[128 * 32];
    int tid = threadIdx.x;
    int lane = tid & 63, w = tid >> 6;
    int l16 = lane & 15, quad = lane >> 4;
    int wm = w >> 1, wn = w & 1;
    int mblk = blockIdx.y * 128, nblk = blockIdx.x * 128;

    f32x4 acc[4][4] = {};

    const bf16* gA = A  + (size_t)(mblk + w * 32 + (lane >> 2)) * K + (lane & 3) * 8;
    const bf16* gB = BT + (size_t)(nblk + w * 32 + (lane >> 2)) * K + (lane & 3) * 8;
    bf16* lA = ldsA + w * 1024;   // wave-uniform
    bf16* lB = ldsB + w * 1024;

    for (int k0 = 0; k0 < K; k0 += 32) {
        gld16(gA + k0,          lA);
        gld16(gA + 16 * K + k0, lA + 512);
        gld16(gB + k0,          lB);
        gld16(gB + 16 * K + k0, lB + 512);
        __syncthreads();
        bf16x8 af[4], bfr[4];
        #pragma unroll
        for (int s = 0; s < 4; s++)
            af[s] = *reinterpret_cast<bf16x8*>(&ldsA[(wm * 64 + s * 16 + l16) * 32 + quad * 8]);
        #pragma unroll
        for (int t = 0; t < 4; t++)
            bfr[t] = *reinterpret_cast<bf16x8*>(&ldsB[(wn * 64 + t * 16 + l16) * 32 + quad * 8]);
        #pragma unroll
        for (int s = 0; s < 4; s++)
            #pragma unroll
            for (int t = 0; t < 4; t++)
                acc[s][t] = __builtin_amdgcn_mfma_f32_16x16x32_bf16(af[s], bfr[t], acc[s][t], 0, 0, 0);
        __syncthreads();
    }

    #pragma unroll
    for (int s = 0; s < 4; s++) {
        int row = mblk + wm * 64 + s * 16 + quad * 4;
        #pragma unroll
        for (int t = 0; t < 4; t++) {
            int col = nblk + wn * 64 + t * 16 + l16;
            #pragma unroll
            for (int r = 0; r < 4; r++) {
                if (OUT_BF16)
                    reinterpret_cast<bf16*>(Cout)[(size_t)(row + r) * ldc + col] = (bf16)acc[s][t][r];
                else
                    reinterpret_cast<float*>(Cout)[(size_t)(row + r) * ldc + col] = acc[s][t][r];
            }
        }
    }
}

// ---------------- RoPE in-place on interleaved qkv [4096][6144] (q,k parts) ----
__global__ void k_rope(bf16* __restrict__ qkv) {
    int id = blockIdx.x * 256 + threadIdx.x;   // 2*B*T*H*32 = 2^23
    int i = id & 31;
    int h = (id >> 5) & 31;
    int t = (id >> 10) & 2047;
    int b = (id >> 21) & 1;
    int sel = id >> 22;                        // 0=q, 1=k
    size_t base = ((size_t)(b * T_ + t)) * 6144 + sel * 2048 + h * 64;
    float inv = expf(-(float)i * (9.210340371976184f / 32.0f));
    float ang = (float)t * inv;
    float s, c;
    sincosf(ang, &s, &c);
    float x1 = (float)qkv[base + i];
    float x2 = (float)qkv[base + i + 32];
    qkv[base + i]      = (bf16)(x1 * c - x2 * s);
    qkv[base + i + 32] = (bf16)(x2 * c + x1 * s);
}

// ---------------- v = l1*v1 + l2*v_gemm -> vT [B,H,DH,T] bf16 ----------------
__global__ void k_combinev(const float* __restrict__ v1, const bf16* __restrict__ qkv,
                           const float* __restrict__ l1p, const float* __restrict__ l2p,
                           bf16* __restrict__ vT) {
    __shared__ float tile[64 * 33];
    float l1 = l1p[0], l2 = l2p[0];
    int b = blockIdx.y >> 5, h = blockIdx.y & 31;
    int t0 = blockIdx.x * 32;
    int tid = threadIdx.x;
    int d = tid & 63, tr = tid >> 6;
    #pragma unroll
    for (int i = 0; i < 8; i++) {
        int t = t0 + i * 4 + tr;
        size_t iv1 = ((size_t)(b * T_ + t)) * 2048 + h * 64 + d;
        size_t ivg = ((size_t)(b * T_ + t)) * 6144 + 4096 + h * 64 + d;
        tile[d * 33 + i * 4 + tr] = l1 * v1[iv1] + l2 * (float)qkv[ivg];
    }
    __syncthreads();
    int tl = tid & 31, dr = tid >> 5;
    #pragma unroll
    for (int j = 0; j < 8; j++) {
        int d2 = dr + j * 8;
        vT[((size_t)((b * H_ + h) * 64 + d2)) * T_ + t0 + tl] = (bf16)tile[d2 * 33 + tl];
    }
}

// ---------------- causal flash attention, S^T formulation ----------------
// block 256 (4 waves), 32 queries/wave = 128 q/block; 64-key tiles in LDS.
// S^T = K @ Q^T: per-query softmax state lives per-lane (col=l16).
// P^T (C-layout) feeds mfma_16x16x16bf16_1k B-operand directly (no LDS round-trip).
__global__ __launch_bounds__(256)
void k_attn(const bf16* __restrict__ qkv, const bf16* __restrict__ vT, bf16* __restrict__ o) {
    __shared__ bf16 ldsK[64 * 72];   // [key][dh], stride 72
    __shared__ bf16 ldsV[64 * 72];   // [dh][key], stride 72
    int qt = blockIdx.x;             // 0..15: queries qt*128..+127
    int bh = blockIdx.y;             // b*32+h
    int b = bh >> 5, h = bh & 31;
    int tid = threadIdx.x;
    int lane = tid & 63, w = tid >> 6;
    int l16 = lane & 15, quad = lane >> 4;

    // Q fragments, prescaled by 1/sqrt(64) * log2(e)
    int qbase = qt * 128 + w * 32;
    bf16x8 qf[2][2];
    #pragma unroll
    for (int qs = 0; qs < 2; qs++) {
        size_t qrow = (size_t)(b * T_ + qbase + qs * 16 + l16) * 6144 + h * 64;
        #pragma unroll
        for (int half = 0; half < 2; half++) {
            bf16x8 v = load8(qkv + qrow + half * 32 + quad * 8);
            #pragma unroll
            for (int e = 0; e < 8; e++) v[e] = (bf16)((float)v[e] * 0.1803368801f);
            qf[qs][half] = v;
        }
    }

    f32x4 accO[2][4] = {};
    float m_[2] = {-1e30f, -1e30f};
    float l_[2] = {0.f, 0.f};

    int srow = tid >> 3, sseg = tid & 7;   // staging: 32 rows x 8 x 16B per pass
    const bf16* kg = qkv + (size_t)(b * T_) * 6144 + 2048 + h * 64 + sseg * 8;
    const bf16* vg = vT + (size_t)bh * DH * T_ + sseg * 8;

    int nkt = 2 * qt + 2;
    for (int kt = 0; kt < nkt; kt++) {
        int key0 = kt * 64;
        #pragma unroll
        for (int j = 0; j < 2; j++) {
            int row = j * 32 + srow;
            *reinterpret_cast<uint4*>(&ldsK[row * 72 + sseg * 8]) =
                *reinterpret_cast<const uint4*>(kg + (size_t)(key0 + row) * 6144);
            *reinterpret_cast<uint4*>(&ldsV[row * 72 + sseg * 8]) =
                *reinterpret_cast<const uint4*>(vg + (size_t)row * T_ + key0);
        }
        __syncthreads();

        // ---- S^T tiles: st[qs][ks][r] = score(key=ks*16+quad*4+r, query=qbase+qs*16+l16)
        f32x4 st[2][4];
        #pragma unroll
        for (int ks = 0; ks < 4; ks++) {
            bf16x8 kf0 = *reinterpret_cast<bf16x8*>(&ldsK[(ks * 16 + l16) * 72 + quad * 8]);
            bf16x8 kf1 = *reinterpret_cast<bf16x8*>(&ldsK[(ks * 16 + l16) * 72 + 32 + quad * 8]);
            #pragma unroll
            for (int qs = 0; qs < 2; qs++) {
                f32x4 z = {};
                z = __builtin_amdgcn_mfma_f32_16x16x32_bf16(kf0, qf[qs][0], z, 0, 0, 0);
                z = __builtin_amdgcn_mfma_f32_16x16x32_bf16(kf1, qf[qs][1], z, 0, 0, 0);
                st[qs][ks] = z;
            }
        }

        // ---- online softmax (per-lane query state) + pack P^T ----
        sv4 pk[2][4];
        #pragma unroll
        for (int qs = 0; qs < 2; qs++) {
            int qcol = qbase + qs * 16 + l16;
            #pragma unroll
            for (int ks = 0; ks < 4; ks++) {
                if (key0 + ks * 16 + 15 > qbase + qs * 16) {   // wave-uniform guard
                    #pragma unroll
                    for (int r = 0; r < 4; r++)
                        if (key0 + ks * 16 + quad * 4 + r > qcol) st[qs][ks][r] = -3e38f;
                }
            }
            float mx = st[qs][0][0];
            #pragma unroll
            for (int ks = 0; ks < 4; ks++)
                #pragma unroll
                for (int r = 0; r < 4; r++) mx = fmaxf(mx, st[qs][ks][r]);
            mx = fmaxf(mx, __shfl_xor(mx, 16));
            mx = fmaxf(mx, __shfl_xor(mx, 32));
            float nm = fmaxf(m_[qs], mx);
            float alpha = __builtin_amdgcn_exp2f(m_[qs] - nm);
            m_[qs] = nm;
            float rsum = 0.f;
            #pragma unroll
            for (int ks = 0; ks < 4; ks++) {
                bf16x4 ph;
                #pragma unroll
                for (int r = 0; r < 4; r++) {
                    float p = __builtin_amdgcn_exp2f(st[qs][ks][r] - nm);
                    rsum += p;
                    ph[r] = (bf16)p;
                }
                pk[qs][ks] = __builtin_bit_cast(sv4, ph);
            }
            rsum += __shfl_xor(rsum, 16);
            rsum += __shfl_xor(rsum, 32);
            l_[qs] = l_[qs] * alpha + rsum;
            #pragma unroll
            for (int n2 = 0; n2 < 4; n2++) accO[qs][n2] *= alpha;
        }

        // ---- O^T += V^T @ P^T  (16x16x16, K=16 per key-group) ----
        #pragma unroll
        for (int ks = 0; ks < 4; ks++) {
            #pragma unroll
            for (int n2 = 0; n2 < 4; n2++) {
                sv4 vf = *reinterpret_cast<sv4*>(&ldsV[(n2 * 16 + l16) * 72 + ks * 16 + quad * 4]);
                #pragma unroll
                for (int qs = 0; qs < 2; qs++)
                    accO[qs][n2] = __builtin_amdgcn_mfma_f32_16x16x16bf16_1k(
                        vf, pk[qs][ks], accO[qs][n2], 0, 0, 0);
            }
        }
        __syncthreads();
    }

    // ---- epilogue: O[d][query] -> o[query][h*64+d], 8B stores ----
    #pragma unroll
    for (int qs = 0; qs < 2; qs++) {
        float inv = 1.0f / l_[qs];
        int query = qbase + qs * 16 + l16;
        #pragma unroll
        for (int n2 = 0; n2 < 4; n2++) {
            bf16x4 ov;
            #pragma unroll
            for (int r = 0; r < 4; r++) ov[r] = (bf16)(accO[qs][n2][r] * inv);
            *reinterpret_cast<bf16x4*>(
                &o[(size_t)(b * T_ + query) * DM + h * 64 + n2 * 16 + quad * 4]) = ov;
        }
    }
}

extern "C" void kernel_launch(void* const* d_in, const int* in_sizes, int n_in,
                              void* d_out, int out_size, void* d_ws, size_t ws_size,
                              hipStream_t stream) {
    const float* hs   = (const float*)d_in[0];
    const float* v1   = (const float*)d_in[1];
    const float* lam1 = (const float*)d_in[2];
    const float* Wq   = (const float*)d_in[3];
    const float* Wk   = (const float*)d_in[4];
    const float* Wv   = (const float*)d_in[5];
    const float* Wo   = (const float*)d_in[6];
    const float* lam2 = (const float*)d_in[7];

    char* ws = (char*)d_ws;
    bf16* hs_bf = (bf16*)(ws);                            // 16 MiB
    bf16* Wcat  = (bf16*)(ws + 16777216);                 // WqT|WkT|WvT, 24 MiB
    bf16* WoT   = (bf16*)(ws + 41943040);                 // 8 MiB
    bf16* qkv   = (bf16*)(ws + 50331648);                 // 4096x6144 bf16 = 48 MiB
    bf16* vT_bf = (bf16*)(ws + 100663296);                // 16 MiB
    bf16* o_bf  = (bf16*)(ws + 117440512);                // 16 MiB -> 128 MiB total

    k_convert<<<8192, 256, 0, stream>>>(hs, hs_bf, 2097152);
    k_transposeW<<<dim3(64, 64, 4), dim3(32, 8), 0, stream>>>(
        Wq, Wk, Wv, Wo, Wcat, Wcat + 4194304, Wcat + 8388608, WoT);

    k_gemm<1><<<dim3(48, 32), 256, 0, stream>>>(hs_bf, Wcat, (void*)qkv, 6144);

    k_rope<<<32768, 256, 0, stream>>>(qkv);
    k_combinev<<<dim3(64, 64), 256, 0, stream>>>(v1, qkv, lam1, lam2, vT_bf);

    k_attn<<<dim3(16, 64), 256, 0, stream>>>(qkv, vT_bf, o_bf);

    k_gemm<0><<<dim3(16, 32), 256, 0, stream>>>(o_bf, WoT, d_out, 2048);
}

// Round 4
// 445.076 us; speedup vs baseline: 1.9124x; 1.1514x over previous
//
#include <hip/hip_runtime.h>
#include <hip/hip_bf16.h>
#include <math.h>

typedef __bf16 bf16;
typedef __bf16 bf16x8 __attribute__((ext_vector_type(8)));
typedef __bf16 bf16x4 __attribute__((ext_vector_type(4)));
typedef float  f32x4  __attribute__((ext_vector_type(4)));
typedef short  sv4    __attribute__((ext_vector_type(4)));

#define B_  2
#define T_  2048
#define DM  2048
#define H_  32
#define DH  64

__device__ __forceinline__ bf16x8 load8(const bf16* p) {
    return *reinterpret_cast<const bf16x8*>(p);
}

__device__ __forceinline__ void gld16(const bf16* g, bf16* l) {
    __builtin_amdgcn_global_load_lds(
        (const __attribute__((address_space(1))) unsigned int*)g,
        (__attribute__((address_space(3))) unsigned int*)l, 16, 0, 0);
}

// ---------------- convert fp32 -> bf16 ----------------
__global__ void k_convert(const float* __restrict__ in, bf16* __restrict__ out, int n4) {
    int i = blockIdx.x * blockDim.x + threadIdx.x;
    if (i < n4) {
        float4 v = reinterpret_cast<const float4*>(in)[i];
        bf16x4 o;
        o[0] = (bf16)v.x; o[1] = (bf16)v.y; o[2] = (bf16)v.z; o[3] = (bf16)v.w;
        reinterpret_cast<bf16x4*>(out)[i] = o;
    }
}

// ---------------- transpose + convert weights ----------------
__global__ void k_transposeW(const float* __restrict__ Wq, const float* __restrict__ Wk,
                             const float* __restrict__ Wv, const float* __restrict__ Wo,
                             bf16* __restrict__ WqT, bf16* __restrict__ WkT,
                             bf16* __restrict__ WvT, bf16* __restrict__ WoT) {
    const float* in; bf16* out;
    switch (blockIdx.z) {
        case 0: in = Wq; out = WqT; break;
        case 1: in = Wk; out = WkT; break;
        case 2: in = Wv; out = WvT; break;
        default: in = Wo; out = WoT; break;
    }
    __shared__ float tile[32][33];
    int tx = threadIdx.x, ty = threadIdx.y;
    int x0 = blockIdx.x * 32, y0 = blockIdx.y * 32;
    #pragma unroll
    for (int i = 0; i < 4; i++)
        tile[ty + i*8][tx] = in[(size_t)(y0 + ty + i*8) * DM + x0 + tx];
    __syncthreads();
    #pragma unroll
    for (int i = 0; i < 4; i++)
        out[(size_t)(x0 + ty + i*8) * DM + y0 + tx] = (bf16)tile[tx][ty + i*8];
}

// ---------------- m97-style GEMM: C[M,*] = A[M,2048] @ BT[N,2048]^T ----------
template<int OUT_BF16>
__global__ __launch_bounds__(256)
void k_gemm(const bf16* __restrict__ A, const bf16* __restrict__ BT,
            void* __restrict__ Cout, int ldc) {
    constexpr int K = 2048;
    __shared__ bf16 ldsA[128 * 32];
    __shared__ bf16 ldsB[128 * 32];
    int tid = threadIdx.x;
    int lane = tid & 63, w = tid >> 6;
    int l16 = lane & 15, quad = lane >> 4;
    int wm = w >> 1, wn = w & 1;
    int mblk = blockIdx.y * 128, nblk = blockIdx.x * 128;

    f32x4 acc[4][4] = {};

    const bf16* gA = A  + (size_t)(mblk + w * 32 + (lane >> 2)) * K + (lane & 3) * 8;
    const bf16* gB = BT + (size_t)(nblk + w * 32 + (lane >> 2)) * K + (lane & 3) * 8;
    bf16* lA = ldsA + w * 1024;
    bf16* lB = ldsB + w * 1024;

    for (int k0 = 0; k0 < K; k0 += 32) {
        gld16(gA + k0,          lA);
        gld16(gA + 16 * K + k0, lA + 512);
        gld16(gB + k0,          lB);
        gld16(gB + 16 * K + k0, lB + 512);
        __syncthreads();
        bf16x8 af[4], bfr[4];
        #pragma unroll
        for (int s = 0; s < 4; s++)
            af[s] = *reinterpret_cast<bf16x8*>(&ldsA[(wm * 64 + s * 16 + l16) * 32 + quad * 8]);
        #pragma unroll
        for (int t = 0; t < 4; t++)
            bfr[t] = *reinterpret_cast<bf16x8*>(&ldsB[(wn * 64 + t * 16 + l16) * 32 + quad * 8]);
        #pragma unroll
        for (int s = 0; s < 4; s++)
            #pragma unroll
            for (int t = 0; t < 4; t++)
                acc[s][t] = __builtin_amdgcn_mfma_f32_16x16x32_bf16(af[s], bfr[t], acc[s][t], 0, 0, 0);
        __syncthreads();
    }

    #pragma unroll
    for (int s = 0; s < 4; s++) {
        int row = mblk + wm * 64 + s * 16 + quad * 4;
        #pragma unroll
        for (int t = 0; t < 4; t++) {
            int col = nblk + wn * 64 + t * 16 + l16;
            #pragma unroll
            for (int r = 0; r < 4; r++) {
                if (OUT_BF16)
                    reinterpret_cast<bf16*>(Cout)[(size_t)(row + r) * ldc + col] = (bf16)acc[s][t][r];
                else
                    reinterpret_cast<float*>(Cout)[(size_t)(row + r) * ldc + col] = acc[s][t][r];
            }
        }
    }
}

// ---------------- RoPE in-place on interleaved qkv [4096][6144] --------------
__global__ void k_rope(bf16* __restrict__ qkv) {
    int id = blockIdx.x * 256 + threadIdx.x;
    int i = id & 31;
    int h = (id >> 5) & 31;
    int t = (id >> 10) & 2047;
    int b = (id >> 21) & 1;
    int sel = id >> 22;
    size_t base = ((size_t)(b * T_ + t)) * 6144 + sel * 2048 + h * 64;
    float inv = expf(-(float)i * (9.210340371976184f / 32.0f));
    float ang = (float)t * inv;
    float s, c;
    sincosf(ang, &s, &c);
    float x1 = (float)qkv[base + i];
    float x2 = (float)qkv[base + i + 32];
    qkv[base + i]      = (bf16)(x1 * c - x2 * s);
    qkv[base + i + 32] = (bf16)(x2 * c + x1 * s);
}

// ---------------- v = l1*v1 + l2*v_gemm -> vT [B,H,DH,T] bf16 ----------------
__global__ void k_combinev(const float* __restrict__ v1, const bf16* __restrict__ qkv,
                           const float* __restrict__ l1p, const float* __restrict__ l2p,
                           bf16* __restrict__ vT) {
    __shared__ float tile[64 * 33];
    float l1 = l1p[0], l2 = l2p[0];
    int b = blockIdx.y >> 5, h = blockIdx.y & 31;
    int t0 = blockIdx.x * 32;
    int tid = threadIdx.x;
    int d = tid & 63, tr = tid >> 6;
    #pragma unroll
    for (int i = 0; i < 8; i++) {
        int t = t0 + i * 4 + tr;
        size_t iv1 = ((size_t)(b * T_ + t)) * 2048 + h * 64 + d;
        size_t ivg = ((size_t)(b * T_ + t)) * 6144 + 4096 + h * 64 + d;
        tile[d * 33 + i * 4 + tr] = l1 * v1[iv1] + l2 * (float)qkv[ivg];
    }
    __syncthreads();
    int tl = tid & 31, dr = tid >> 5;
    #pragma unroll
    for (int j = 0; j < 8; j++) {
        int d2 = dr + j * 8;
        vT[((size_t)((b * H_ + h) * 64 + d2)) * T_ + t0 + tl] = (bf16)tile[d2 * 33 + tl];
    }
}

// ---------------- causal flash attention, S^T form, load-balanced ------------
// block 256 (4 waves); each block runs TWO q-tiles (bx and 15-bx) sequentially
// -> uniform 34 key-tiles per block. 32 queries/wave, 64-key LDS tiles.
__global__ __launch_bounds__(256)
void k_attn(const bf16* __restrict__ qkv, const bf16* __restrict__ vT, bf16* __restrict__ o) {
    __shared__ bf16 ldsK[64 * 72];   // [key][dh] stride 72
    __shared__ bf16 ldsV[64 * 68];   // [dh][key] stride 68 (2-way-free on 8B reads)
    int bx = blockIdx.x;             // 0..7
    int bh = blockIdx.y;             // b*32+h
    int b = bh >> 5, h = bh & 31;
    int tid = threadIdx.x;
    int lane = tid & 63, w = tid >> 6;
    int l16 = lane & 15, quad = lane >> 4;

    int srow = tid >> 3, sseg = tid & 7;   // staging: 32 rows x 8 x 16B per j-pass
    const bf16* kg = qkv + (size_t)(b * T_) * 6144 + 2048 + h * 64 + sseg * 8;
    const bf16* vg = vT + (size_t)bh * DH * T_ + sseg * 8;

    #pragma unroll 1
    for (int pass = 0; pass < 2; pass++) {
        int qt = pass ? (15 - bx) : bx;
        int qbase = qt * 128 + w * 32;

        // Q fragments, prescaled by 1/sqrt(64) * log2(e)
        bf16x8 qf[2][2];
        #pragma unroll
        for (int qs = 0; qs < 2; qs++) {
            size_t qrow = (size_t)(b * T_ + qbase + qs * 16 + l16) * 6144 + h * 64;
            #pragma unroll
            for (int half = 0; half < 2; half++) {
                bf16x8 v = load8(qkv + qrow + half * 32 + quad * 8);
                #pragma unroll
                for (int e = 0; e < 8; e++) v[e] = (bf16)((float)v[e] * 0.1803368801f);
                qf[qs][half] = v;
            }
        }

        f32x4 accO[2][4] = {};
        float m_[2] = {-1e30f, -1e30f};
        float pl[2] = {0.f, 0.f};     // per-lane partial row-sums (reduced at end)

        int nkt = 2 * qt + 2;
        for (int kt = 0; kt < nkt; kt++) {
            int key0 = kt * 64;
            #pragma unroll
            for (int j = 0; j < 2; j++) {
                int row = j * 32 + srow;
                *reinterpret_cast<uint4*>(&ldsK[row * 72 + sseg * 8]) =
                    *reinterpret_cast<const uint4*>(kg + (size_t)(key0 + row) * 6144);
                *reinterpret_cast<uint4*>(&ldsV[row * 68 + sseg * 8]) =
                    *reinterpret_cast<const uint4*>(vg + (size_t)row * T_ + key0);
            }
            __syncthreads();

            // ---- S^T: st[qs][ks][r] = score(key=key0+ks*16+quad*4+r, query=qbase+qs*16+l16)
            f32x4 st[2][4];
            #pragma unroll
            for (int ks = 0; ks < 4; ks++) {
                bf16x8 kf0 = *reinterpret_cast<bf16x8*>(&ldsK[(ks * 16 + l16) * 72 + quad * 8]);
                bf16x8 kf1 = *reinterpret_cast<bf16x8*>(&ldsK[(ks * 16 + l16) * 72 + 32 + quad * 8]);
                #pragma unroll
                for (int qs = 0; qs < 2; qs++) {
                    f32x4 z = {};
                    z = __builtin_amdgcn_mfma_f32_16x16x32_bf16(kf0, qf[qs][0], z, 0, 0, 0);
                    z = __builtin_amdgcn_mfma_f32_16x16x32_bf16(kf1, qf[qs][1], z, 0, 0, 0);
                    st[qs][ks] = z;
                }
            }

            // ---- online softmax (per-lane query state) + pack P^T ----
            sv4 pk[2][4];
            #pragma unroll
            for (int qs = 0; qs < 2; qs++) {
                int qcol = qbase + qs * 16 + l16;
                #pragma unroll
                for (int ks = 0; ks < 4; ks++) {
                    if (key0 + ks * 16 + 15 > qbase + qs * 16) {   // wave-uniform guard
                        #pragma unroll
                        for (int r = 0; r < 4; r++)
                            if (key0 + ks * 16 + quad * 4 + r > qcol) st[qs][ks][r] = -3e38f;
                    }
                }
                float mx = st[qs][0][0];
                #pragma unroll
                for (int ks = 0; ks < 4; ks++)
                    #pragma unroll
                    for (int r = 0; r < 4; r++) mx = fmaxf(mx, st[qs][ks][r]);
                mx = fmaxf(mx, __shfl_xor(mx, 16));
                mx = fmaxf(mx, __shfl_xor(mx, 32));
                if (__any(mx > m_[qs])) {          // wave-uniform rescale (rare late in scan)
                    float nm = fmaxf(m_[qs], mx);
                    float alpha = __builtin_amdgcn_exp2f(m_[qs] - nm);
                    m_[qs] = nm;
                    pl[qs] *= alpha;
                    #pragma unroll
                    for (int n2 = 0; n2 < 4; n2++) accO[qs][n2] *= alpha;
                }
                float nm = m_[qs];
                float rsum = 0.f;
                #pragma unroll
                for (int ks = 0; ks < 4; ks++) {
                    bf16x4 ph;
                    #pragma unroll
                    for (int r = 0; r < 4; r++) {
                        float p = __builtin_amdgcn_exp2f(st[qs][ks][r] - nm);
                        rsum += p;
                        ph[r] = (bf16)p;
                    }
                    pk[qs][ks] = __builtin_bit_cast(sv4, ph);
                }
                pl[qs] += rsum;
            }

            // ---- O^T += V^T @ P^T (16x16x16) ----
            #pragma unroll
            for (int ks = 0; ks < 4; ks++) {
                #pragma unroll
                for (int n2 = 0; n2 < 4; n2++) {
                    sv4 vf = *reinterpret_cast<sv4*>(&ldsV[(n2 * 16 + l16) * 68 + ks * 16 + quad * 4]);
                    #pragma unroll
                    for (int qs = 0; qs < 2; qs++)
                        accO[qs][n2] = __builtin_amdgcn_mfma_f32_16x16x16bf16_1k(
                            vf, pk[qs][ks], accO[qs][n2], 0, 0, 0);
                }
            }
            __syncthreads();
        }

        // ---- epilogue: cross-quad l reduction, O scale, store ----
        #pragma unroll
        for (int qs = 0; qs < 2; qs++) {
            float l = pl[qs];
            l += __shfl_xor(l, 16);
            l += __shfl_xor(l, 32);
            float inv = 1.0f / l;
            int query = qbase + qs * 16 + l16;
            #pragma unroll
            for (int n2 = 0; n2 < 4; n2++) {
                bf16x4 ov;
                #pragma unroll
                for (int r = 0; r < 4; r++) ov[r] = (bf16)(accO[qs][n2][r] * inv);
                *reinterpret_cast<bf16x4*>(
                    &o[(size_t)(b * T_ + query) * DM + h * 64 + n2 * 16 + quad * 4]) = ov;
            }
        }
    }
}

extern "C" void kernel_launch(void* const* d_in, const int* in_sizes, int n_in,
                              void* d_out, int out_size, void* d_ws, size_t ws_size,
                              hipStream_t stream) {
    const float* hs   = (const float*)d_in[0];
    const float* v1   = (const float*)d_in[1];
    const float* lam1 = (const float*)d_in[2];
    const float* Wq   = (const float*)d_in[3];
    const float* Wk   = (const float*)d_in[4];
    const float* Wv   = (const float*)d_in[5];
    const float* Wo   = (const float*)d_in[6];
    const float* lam2 = (const float*)d_in[7];

    char* ws = (char*)d_ws;
    bf16* hs_bf = (bf16*)(ws);                            // 16 MiB
    bf16* Wcat  = (bf16*)(ws + 16777216);                 // WqT|WkT|WvT, 24 MiB
    bf16* WoT   = (bf16*)(ws + 41943040);                 // 8 MiB
    bf16* qkv   = (bf16*)(ws + 50331648);                 // 4096x6144 bf16 = 48 MiB
    bf16* vT_bf = (bf16*)(ws + 100663296);                // 16 MiB
    bf16* o_bf  = (bf16*)(ws + 117440512);                // 16 MiB -> 128 MiB

    k_convert<<<8192, 256, 0, stream>>>(hs, hs_bf, 2097152);
    k_transposeW<<<dim3(64, 64, 4), dim3(32, 8), 0, stream>>>(
        Wq, Wk, Wv, Wo, Wcat, Wcat + 4194304, Wcat + 8388608, WoT);

    k_gemm<1><<<dim3(48, 32), 256, 0, stream>>>(hs_bf, Wcat, (void*)qkv, 6144);

    k_rope<<<32768, 256, 0, stream>>>(qkv);
    k_combinev<<<dim3(64, 64), 256, 0, stream>>>(v1, qkv, lam1, lam2, vT_bf);

    k_attn<<<dim3(8, 64), 256, 0, stream>>>(qkv, vT_bf, o_bf);

    k_gemm<0><<<dim3(16, 32), 256, 0, stream>>>(o_bf, WoT, d_out, 2048);
}